// Round 15
// baseline (194.877 us; speedup 1.0000x reference)
//
#include <hip/hip_runtime.h>
#include <hip/hip_bf16.h>

#define BB 8
#define NN 16384
#define CC 128

typedef __attribute__((ext_vector_type(8))) short bf16x8;
typedef __attribute__((ext_vector_type(4))) short short4v;
typedef __attribute__((ext_vector_type(4))) float f32x4;

__device__ __forceinline__ unsigned short f2bf(float f) {
    union { float f; unsigned u; } v; v.f = f;
    unsigned r = v.u + 0x7fffu + ((v.u >> 16) & 1u);
    return (unsigned short)(r >> 16);
}
__device__ __forceinline__ float bf2f(unsigned short h) {
    union { unsigned u; float f; } v; v.u = ((unsigned)h) << 16;
    return v.f;
}
// truncating hi/lo split: lo captures the residual, RNE on hi unnecessary
__device__ __forceinline__ void split_trunc(float f, short& hi, short& lo) {
    union { float f; unsigned u; } v; v.f = f;
    const unsigned short hu = (unsigned short)(v.u >> 16);
    union { unsigned u; float f; } hf; hf.u = ((unsigned)hu) << 16;
    union { float f; unsigned u; } r; r.f = f - hf.f;
    hi = (short)hu;
    lo = (short)(r.u >> 16);
}

// ---------------------------------------------------------------------------
// W prep: split Wq/Wkv/Wproj into bf16 hi/lo (blocks 0-47); block 48
// precomputes sps[c] = 1/softplus(scale[c]). grid 49, block 256.
// ---------------------------------------------------------------------------
__global__ __launch_bounds__(256) void wprep_kernel(
    const float* __restrict__ Wq, const float* __restrict__ Wkv,
    const float* __restrict__ Wp, const float* __restrict__ scale,
    unsigned short* __restrict__ whi, unsigned short* __restrict__ wlo,
    float* __restrict__ sps)
{
    const int bid = blockIdx.x;
    if (bid == 48) {
        if (threadIdx.x < 128)
            sps[threadIdx.x] = 1.f / log1pf(expf(scale[threadIdx.x]));
        return;
    }
    const int mat = bid >> 4;
    const float* src = (mat == 0) ? Wq : ((mat == 1) ? Wkv : Wp);
    const int off = (bid & 15) * 1024 + threadIdx.x * 4;
    const float4 v = *(const float4*)(src + off);
    float f[4] = {v.x, v.y, v.z, v.w};
    short4v hv, lv;
#pragma unroll
    for (int j = 0; j < 4; ++j) {
        short h, lo2;
        split_trunc(f[j], h, lo2);
        hv[j] = h; lv[j] = lo2;
    }
    *(short4v*)(whi + mat * 16384 + off) = hv;
    *(short4v*)(wlo + mat * 16384 + off) = lv;
}

// ---------------------------------------------------------------------------
// qk v9 (R14, unchanged — fell out of top-5): fused q+k MFMA with W staged
// in LDS (128KB), region reused for transposes + k_t scatter.
// grid 1024, block 256 (4 waves x 32 tokens).
// ---------------------------------------------------------------------------
__global__ __launch_bounds__(256, 1) void qk_mfma_kernel(
    const float* __restrict__ x, const unsigned short* __restrict__ whi,
    const unsigned short* __restrict__ wlo, const float* __restrict__ w_g,
    const float* __restrict__ sps, const float* __restrict__ pos_enc,
    unsigned short* __restrict__ qout, unsigned short* __restrict__ kout,
    unsigned short* __restrict__ ktout, float* __restrict__ partial)
{
    __shared__ __align__(16) char wsm[131072];
    __shared__ float wpart[4][257];
    __shared__ float apl[128];

    const int tid  = threadIdx.x;
    const int w    = tid >> 6;
    const int l    = tid & 63;
    const int blk  = blockIdx.x;
    const int tok0 = blk * 128;
    const int tokb = (blk & 127) * 128;

    bf16x8 xh[2][4], xl[2][4];
#pragma unroll
    for (int n = 0; n < 2; ++n) {
        const int r = w * 32 + n * 16 + (l & 15);
        const float* rowp = x + (tok0 + r) * 128 + (l >> 4) * 8;
#pragma unroll
        for (int kt = 0; kt < 4; ++kt) {
            const f32x4 a = *(const f32x4*)(rowp + kt * 32);
            const f32x4 b = *(const f32x4*)(rowp + kt * 32 + 4);
            const float f[8] = {a[0], a[1], a[2], a[3], b[0], b[1], b[2], b[3]};
            bf16x8 hv, lv;
#pragma unroll
            for (int j = 0; j < 8; ++j) {
                short h, lo2;
                split_trunc(f[j], h, lo2);
                hv[j] = h; lv[j] = lo2;
            }
            xh[n][kt] = hv; xl[n][kt] = lv;
        }
    }

#pragma unroll
    for (int it = 0; it < 32; ++it) {
        const int flat = it * 256 + tid;
        const int arr  = flat >> 11;
        const int c    = (flat >> 4) & 127;
        const int g    = flat & 15;
        const unsigned short* src = ((arr & 1) ? wlo : whi)
                                  + ((arr >> 1) ? 16384 : 0) + c * 128 + g * 8;
        const int dst = arr * 32768 + c * 256 + ((g * 16) ^ ((c & 7) << 4));
        *(bf16x8*)(wsm + dst) = *(const bf16x8*)src;
    }
    __syncthreads();

    const int crow = (l >> 4) * 4;
    f32x4 accq[8][2], acck[8][2];
#pragma unroll
    for (int m = 0; m < 8; ++m)
#pragma unroll
        for (int n = 0; n < 2; ++n) { accq[m][n] = (f32x4)0.f; acck[m][n] = (f32x4)0.f; }

#pragma unroll
    for (int m = 0; m < 8; ++m) {
        const int c = m * 16 + (l & 15);
        const int sw = (c & 7) << 4;
        bf16x8 aqh[4], aql[4], akh[4], akl[4];
#pragma unroll
        for (int kt = 0; kt < 4; ++kt) {
            const int fo = c * 256 + ((kt * 64 + (l >> 4) * 16) ^ sw);
            aqh[kt] = *(const bf16x8*)(wsm + fo);
            aql[kt] = *(const bf16x8*)(wsm + 32768 + fo);
            akh[kt] = *(const bf16x8*)(wsm + 65536 + fo);
            akl[kt] = *(const bf16x8*)(wsm + 98304 + fo);
        }
#pragma unroll
        for (int n = 0; n < 2; ++n)
#pragma unroll
            for (int kt = 0; kt < 4; ++kt) {
                accq[m][n] = __builtin_amdgcn_mfma_f32_16x16x32_bf16(aqh[kt], xh[n][kt], accq[m][n], 0, 0, 0);
                acck[m][n] = __builtin_amdgcn_mfma_f32_16x16x32_bf16(akh[kt], xh[n][kt], acck[m][n], 0, 0, 0);
                accq[m][n] = __builtin_amdgcn_mfma_f32_16x16x32_bf16(aqh[kt], xl[n][kt], accq[m][n], 0, 0, 0);
                acck[m][n] = __builtin_amdgcn_mfma_f32_16x16x32_bf16(akh[kt], xl[n][kt], acck[m][n], 0, 0, 0);
                accq[m][n] = __builtin_amdgcn_mfma_f32_16x16x32_bf16(aql[kt], xh[n][kt], accq[m][n], 0, 0, 0);
                acck[m][n] = __builtin_amdgcn_mfma_f32_16x16x32_bf16(akl[kt], xh[n][kt], acck[m][n], 0, 0, 0);
            }
    }
    __syncthreads();

    // ---- q epilogue ----
    {
#pragma unroll
        for (int m = 0; m < 8; ++m) {
            const float4 is4 = *(const float4*)(sps + m * 16 + crow);
            const float is[4] = {is4.x, is4.y, is4.z, is4.w};
#pragma unroll
            for (int n = 0; n < 2; ++n)
#pragma unroll
                for (int j = 0; j < 4; ++j)
                    accq[m][n][j] = (fmaxf(accq[m][n][j], 0.f) + 1e-6f) * is[j];
        }
        float fqn[2];
#pragma unroll
        for (int n = 0; n < 2; ++n) {
            float s2 = 0.f, s6 = 0.f;
#pragma unroll
            for (int m = 0; m < 8; ++m)
#pragma unroll
                for (int j = 0; j < 4; ++j) {
                    const float v = accq[m][n][j], v2 = v * v;
                    s2 += v2; s6 += v2 * v2 * v2;
                }
            s2 += __shfl_xor(s2, 16); s6 += __shfl_xor(s6, 16);
            s2 += __shfl_xor(s2, 32); s6 += __shfl_xor(s6, 32);
            fqn[n] = sqrtf(s2 / s6);
        }
#pragma unroll
        for (int m = 0; m < 8; ++m)
#pragma unroll
            for (int n = 0; n < 2; ++n)
#pragma unroll
                for (int j = 0; j < 4; ++j) {
                    const float v = accq[m][n][j];
                    accq[m][n][j] = v * v * v * fqn[n];
                }
        float d0 = 0.f, d1 = 0.f;
#pragma unroll
        for (int m = 0; m < 8; ++m) {
            const float4 wgv = *(const float4*)(w_g + m * 16 + crow);
#pragma unroll
            for (int j = 0; j < 4; ++j) {
                const float wg = (j == 0) ? wgv.x : (j == 1) ? wgv.y : (j == 2) ? wgv.z : wgv.w;
                d0 += accq[m][0][j] * wg;
                d1 += accq[m][1][j] * wg;
            }
        }
        d0 += __shfl_xor(d0, 16); d0 += __shfl_xor(d0, 32);
        d1 += __shfl_xor(d1, 16); d1 += __shfl_xor(d1, 32);
        const float ap0 = 0.25f * d0, ap1 = 0.25f * d1;

        float ssa = ap0 * ap0 + ap1 * ap1;
        ssa += __shfl_xor(ssa, 1); ssa += __shfl_xor(ssa, 2);
        ssa += __shfl_xor(ssa, 4); ssa += __shfl_xor(ssa, 8);
        if (l == 0) wpart[w][256] = ssa;
        if (l < 16) { apl[w * 32 + l] = ap0; apl[w * 32 + 16 + l] = ap1; }

        float g4[4] = {0.f, 0.f, 0.f, 0.f};
#pragma unroll
        for (int n = 0; n < 2; ++n) {
            const int t = l & 15;
            const int rb = w * 8192 + t * 512;
#pragma unroll
            for (int m = 0; m < 8; ++m) {
                const int ad = rb + (((m * 16 + crow) * 4) ^ ((t & 7) << 4));
                *(f32x4*)(wsm + ad) = accq[m][n];
            }
            asm volatile("s_waitcnt lgkmcnt(0)" ::: "memory");
#pragma unroll
            for (int j = 0; j < 8; ++j) {
                const int fid = j * 64 + l;
                const int row = fid >> 5;
                const int c4  = fid & 31;
                const int rb3 = w * 8192 + row * 512;
                const f32x4 v = *(f32x4*)(wsm + rb3 + ((c4 * 16) ^ ((row & 7) << 4)));
                const float apv = apl[w * 32 + n * 16 + row];
                short4v qv;
#pragma unroll
                for (int i = 0; i < 4; ++i) {
                    g4[i] += apv * v[i];
                    qv[i] = (short)f2bf(v[i]);
                }
                *(short4v*)(qout + (tok0 + w * 32 + n * 16 + row) * 128 + c4 * 4) = qv;
            }
        }
#pragma unroll
        for (int i = 0; i < 4; ++i) g4[i] += __shfl_xor(g4[i], 32);
        if (l < 32) {
#pragma unroll
            for (int i = 0; i < 4; ++i) wpart[w][(l & 31) * 4 + i] = g4[i];
        }
    }

    // ---- k epilogue ----
    {
#pragma unroll
        for (int m = 0; m < 8; ++m) {
            const float4 is4 = *(const float4*)(sps + m * 16 + crow);
            const float is[4] = {is4.x, is4.y, is4.z, is4.w};
#pragma unroll
            for (int n = 0; n < 2; ++n) {
                const int t = tokb + w * 32 + n * 16 + (l & 15);
                const float4 p = *(const float4*)(pos_enc + t * 128 + m * 16 + crow);
                const float pe[4] = {p.x, p.y, p.z, p.w};
#pragma unroll
                for (int j = 0; j < 4; ++j)
                    acck[m][n][j] = (fmaxf(acck[m][n][j] + pe[j], 0.f) + 1e-6f) * is[j];
            }
        }
        float fkn[2];
#pragma unroll
        for (int n = 0; n < 2; ++n) {
            float s2 = 0.f, s6 = 0.f;
#pragma unroll
            for (int m = 0; m < 8; ++m)
#pragma unroll
                for (int j = 0; j < 4; ++j) {
                    const float v = acck[m][n][j], v2 = v * v;
                    s2 += v2; s6 += v2 * v2 * v2;
                }
            s2 += __shfl_xor(s2, 16); s6 += __shfl_xor(s6, 16);
            s2 += __shfl_xor(s2, 32); s6 += __shfl_xor(s6, 32);
            fkn[n] = sqrtf(s2 / s6);
        }
#pragma unroll
        for (int m = 0; m < 8; ++m)
#pragma unroll
            for (int n = 0; n < 2; ++n)
#pragma unroll
                for (int j = 0; j < 4; ++j) {
                    const float v = acck[m][n][j];
                    acck[m][n][j] = v * v * v * fkn[n];
                }
        float ks4[4] = {0.f, 0.f, 0.f, 0.f};
#pragma unroll
        for (int n = 0; n < 2; ++n) {
            const int t = l & 15;
            const int rb = w * 8192 + t * 512;
#pragma unroll
            for (int m = 0; m < 8; ++m) {
                const int ad = rb + (((m * 16 + crow) * 4) ^ ((t & 7) << 4));
                *(f32x4*)(wsm + ad) = acck[m][n];
            }
            asm volatile("s_waitcnt lgkmcnt(0)" ::: "memory");
#pragma unroll
            for (int j = 0; j < 8; ++j) {
                const int fid = j * 64 + l;
                const int row = fid >> 5;
                const int c4  = fid & 31;
                const int rb3 = w * 8192 + row * 512;
                const f32x4 v = *(f32x4*)(wsm + rb3 + ((c4 * 16) ^ ((row & 7) << 4)));
                short4v kv;
#pragma unroll
                for (int i = 0; i < 4; ++i) {
                    ks4[i] += v[i];
                    kv[i] = (short)f2bf(v[i]);
                }
                *(short4v*)(kout + (tok0 + w * 32 + n * 16 + row) * 128 + c4 * 4) = kv;
            }
        }
#pragma unroll
        for (int i = 0; i < 4; ++i) ks4[i] += __shfl_xor(ks4[i], 32);
        if (l < 32) {
#pragma unroll
            for (int i = 0; i < 4; ++i) wpart[w][128 + (l & 31) * 4 + i] = ks4[i];
        }
    }

    __syncthreads();
#pragma unroll
    for (int m = 0; m < 8; ++m)
#pragma unroll
        for (int n = 0; n < 2; ++n)
#pragma unroll
            for (int j = 0; j < 4; ++j) {
                const int ch = m * 16 + crow + j;
                const int tl = w * 32 + n * 16 + (l & 15);
                *(unsigned short*)(wsm + ch * 264 + tl * 2) = f2bf(acck[m][n][j]);
            }
    __syncthreads();
    {
        const int bb = blk >> 7;
        unsigned* ktp = (unsigned*)ktout;
#pragma unroll
        for (int it = 0; it < 32; ++it) {
            const int idx = it * 256 + tid;
            const int row = idx >> 6;
            const int col = idx & 63;
            const unsigned v = *(unsigned*)(wsm + row * 264 + col * 4);
            ktp[(size_t)(bb * 128 + row) * 8192 + (blk & 127) * 64 + col] = v;
        }
    }

    __syncthreads();
    float* pblk = partial + blk * 257;
    if (tid < 128) {
        pblk[tid] = wpart[0][tid] + wpart[1][tid] + wpart[2][tid] + wpart[3][tid];
        pblk[128 + tid] = wpart[0][128 + tid] + wpart[1][128 + tid] +
                          wpart[2][128 + tid] + wpart[3][128 + tid];
    } else if (tid == 128) {
        pblk[256] = wpart[0][256] + wpart[1][256] + wpart[2][256] + wpart[3][256];
    }
}

// ---------------------------------------------------------------------------
// reduce partials -> G, kbar. grid 8, block 256.
// ---------------------------------------------------------------------------
__global__ __launch_bounds__(256) void reduce_kernel(
    const float* __restrict__ partial, float* __restrict__ G,
    float* __restrict__ kbar)
{
    const int b = blockIdx.x;
    const int tid = threadIdx.x;
    __shared__ float tmp[4];

    float ssa = (tid < 128) ? partial[(b * 128 + tid) * 257 + 256] : 0.f;
#pragma unroll
    for (int o = 32; o >= 1; o >>= 1) ssa += __shfl_xor(ssa, o);
    if ((tid & 63) == 0) tmp[tid >> 6] = ssa;
    __syncthreads();
    const float anorm = fmaxf(sqrtf(tmp[0] + tmp[1] + tmp[2] + tmp[3]), 1e-12f);
    const float inv_a = 1.f / anorm;

    if (tid < 128) {
        float g = 0.f;
        for (int t = 0; t < 128; ++t)
            g += partial[(b * 128 + t) * 257 + tid];
        G[b * 128 + tid] = g * inv_a;
    } else {
        const int c2 = tid - 128;
        float s = 0.f;
        for (int t = 0; t < 128; ++t)
            s += partial[(b * 128 + t) * 257 + 128 + c2];
        kbar[b * 128 + c2] = s * (1.f / 16384.f);
    }
}

// ---------------------------------------------------------------------------
// z kernel. grid 2048, block 256.
// ---------------------------------------------------------------------------
__global__ __launch_bounds__(256) void z_kernel(
    const unsigned short* __restrict__ q, const float* __restrict__ kbar,
    float* __restrict__ z)
{
    const int bid = blockIdx.x;
    const int b   = bid >> 8;
    const int tg  = bid & 255;
    const int tid = threadIdx.x;
    const int t   = tid >> 2;
    const int qt  = tid & 3;
    const int tok = tg * 64 + t;

    const unsigned short* qp = q + ((size_t)b * NN + tok) * 128 + qt * 32;
    const float* kb = kbar + b * 128 + qt * 32;

    float dot0 = 0.f, dot1 = 0.f;
#pragma unroll
    for (int c = 0; c < 4; ++c) {
        const short4v q4a = *(const short4v*)(qp + c * 8);
        const short4v q4b = *(const short4v*)(qp + c * 8 + 4);
        const float4 k4a = *(const float4*)(kb + c * 8);
        const float4 k4b = *(const float4*)(kb + c * 8 + 4);
        float d = bf2f((unsigned short)q4a[0]) * k4a.x + bf2f((unsigned short)q4a[1]) * k4a.y +
                  bf2f((unsigned short)q4a[2]) * k4a.z + bf2f((unsigned short)q4a[3]) * k4a.w +
                  bf2f((unsigned short)q4b[0]) * k4b.x + bf2f((unsigned short)q4b[1]) * k4b.y +
                  bf2f((unsigned short)q4b[2]) * k4b.z + bf2f((unsigned short)q4b[3]) * k4b.w;
        if (c < 2) dot0 += d; else dot1 += d;
    }
    z[((size_t)b * 8 + qt * 2) * NN + tok]     = 1.f / (dot0 + 1e-6f);
    z[((size_t)b * 8 + qt * 2 + 1) * NN + tok] = 1.f / (dot1 + 1e-6f);
}

// ---------------------------------------------------------------------------
// scp v2: single-bf16 proj tile (LDS 67.5->~34.5KB), conv half-split with
// interleaved phase-2 (peak conv live regs 144->~80), launch_bounds(256,3).
// R14 counters: 98us, MfmaUtil 5%, occ 17.9% — latency-bound at 2 blocks/CU.
// Tile bf16 adds ~0.3% indep error (absmax 2048 -> ~2500, threshold 6717).
// grid 1024, block 256.
// ---------------------------------------------------------------------------
__global__ __launch_bounds__(256, 3) void scp_kernel(
    float* __restrict__ out, const unsigned short* __restrict__ kbuf,
    const unsigned short* __restrict__ kt, const float* __restrict__ z,
    const float* __restrict__ G,
    const unsigned short* __restrict__ whi, const unsigned short* __restrict__ wlo,
    const float* __restrict__ bp, const float* __restrict__ dwc_w,
    const float* __restrict__ dwc_b)
{
    __shared__ __align__(16) char smem[32768];   // single-bf16 tile / transpose
    __shared__ float wct[25][16];
    __shared__ float bi[16];
    __shared__ float Gs;

    const int tid  = threadIdx.x;
    const int bid0 = blockIdx.x;
    const int bid  = (bid0 & 7) * 128 + (bid0 >> 3);   // bijective XCD swizzle
    const int cc   = bid & 127;
    const int b    = bid >> 7;
    const int n0   = bid * 128;

    for (int i = tid; i < 400; i += 256)
        wct[i >> 4][i & 15] = dwc_w[(i & 15) * 25 + (i >> 4)];
    if (tid < 16) bi[tid] = dwc_b[tid];
    if (tid == 0) Gs = G[b * 128 + cc];
    __syncthreads();

    const int l  = tid & 31;          // ch4 index (channels l*4..l*4+3)
    const int xg = tid >> 5;          // 0..7 (x base xg*16)
    const int dbase = (l & 3) * 4;

    const float Gcc = Gs;
    const unsigned short* kub = kt + ((size_t)b * 128 + cc) * NN;
    const float* zr = z + ((size_t)b * 8 + (cc >> 4)) * NN;
    const float4 b4 = *(const float4*)(&bi[dbase]);
    const float bv[4] = {b4.x, b4.y, b4.z, b4.w};

    // two 8-output halves; phase-2 interleaved so conv acc dies per-half
#pragma unroll
    for (int h = 0; h < 2; ++h) {
        float4 acc[8];
#pragma unroll
        for (int i = 0; i < 8; ++i) acc[i] = make_float4(0.f, 0.f, 0.f, 0.f);

#pragma unroll
        for (int dy = 0; dy < 5; ++dy) {
            const int yy = cc + dy - 2;
            if (yy < 0 || yy > 127) continue;
            const unsigned short* rowb = kbuf + (b * NN + yy * 128) * CC + l * 4;
            float4 rowv[12];
#pragma unroll
            for (int xi = 0; xi < 12; ++xi) {
                const int xx = xg * 16 + h * 8 - 2 + xi;
                if (xx >= 0 && xx < 128) {
                    const short4v kv4 = *(const short4v*)(rowb + xx * CC);
                    rowv[xi] = make_float4(bf2f((unsigned short)kv4[0]),
                                           bf2f((unsigned short)kv4[1]),
                                           bf2f((unsigned short)kv4[2]),
                                           bf2f((unsigned short)kv4[3]));
                } else {
                    rowv[xi] = make_float4(0.f, 0.f, 0.f, 0.f);
                }
            }
#pragma unroll
            for (int dx = 0; dx < 5; ++dx) {
                const float4 wv = *(const float4*)(&wct[dy * 5 + dx][dbase]);
#pragma unroll
                for (int i = 0; i < 8; ++i) {
                    acc[i].x += wv.x * rowv[i + dx].x;
                    acc[i].y += wv.y * rowv[i + dx].y;
                    acc[i].z += wv.z * rowv[i + dx].z;
                    acc[i].w += wv.w * rowv[i + dx].w;
                }
            }
        }

        // phase-2 for this half: u-part + conv + bias -> bf16 tile (single)
#pragma unroll
        for (int i = 0; i < 8; ++i) {
            const int r = xg * 16 + h * 8 + i;
            const int toks = r * 128 + l * 4;
            const short4v ku4 = *(const short4v*)(kub + toks);
            const float4 z4 = *(const float4*)(zr + toks);
            const float zz[4] = {z4.x, z4.y, z4.z, z4.w};
            const float av[4] = {acc[i].x, acc[i].y, acc[i].z, acc[i].w};
            short4v hv;
#pragma unroll
            for (int c = 0; c < 4; ++c) {
                const float f = Gcc * bf2f((unsigned short)ku4[c]) * zz[c] + av[c] + bv[c];
                hv[c] = (short)f2bf(f);
            }
            const int ad = r * 256 + (((l >> 1) * 16) ^ ((r & 7) << 4)) + (l & 1) * 8;
            *(short4v*)(smem + ad) = hv;
        }
    }
    __syncthreads();

    // ---- proj MFMA (A = Wproj hi/lo from L2, B = single-bf16 tile) ----
    const int w  = tid >> 6;
    const int ll = tid & 63;
    bf16x8 xh[2][4];
    {
        const int lg16 = (ll >> 4) * 16;
#pragma unroll
        for (int n = 0; n < 2; ++n) {
            const int r = w * 32 + n * 16 + (ll & 15);
            const int rb = r * 256;
            const int sw = (r & 7) << 4;
#pragma unroll
            for (int kt2 = 0; kt2 < 4; ++kt2)
                xh[n][kt2] = *(bf16x8*)(smem + rb + ((kt2 * 64 + lg16) ^ sw));
        }
    }
    const int crow = (ll >> 4) * 4;
    f32x4 pacc[8][2];
#pragma unroll
    for (int m = 0; m < 8; ++m)
#pragma unroll
        for (int n = 0; n < 2; ++n) pacc[m][n] = (f32x4)0.f;

#pragma unroll
    for (int m = 0; m < 8; ++m) {
        const int c = m * 16 + (ll & 15);
        bf16x8 ah[4], al[4];
#pragma unroll
        for (int kt2 = 0; kt2 < 4; ++kt2) {
            const int off = 32768 + c * 128 + kt2 * 32 + (ll >> 4) * 8;
            ah[kt2] = *(const bf16x8*)(whi + off);
            al[kt2] = *(const bf16x8*)(wlo + off);
        }
#pragma unroll
        for (int n = 0; n < 2; ++n)
#pragma unroll
            for (int kt2 = 0; kt2 < 4; ++kt2) {
                pacc[m][n] = __builtin_amdgcn_mfma_f32_16x16x32_bf16(ah[kt2], xh[n][kt2], pacc[m][n], 0, 0, 0);
                pacc[m][n] = __builtin_amdgcn_mfma_f32_16x16x32_bf16(al[kt2], xh[n][kt2], pacc[m][n], 0, 0, 0);
            }
    }

    // ---- bias + transpose (wave-private 8KB, two sub-phases) + store ----
#pragma unroll
    for (int m = 0; m < 8; ++m) {
        const float4 bq = *(const float4*)(bp + m * 16 + crow);
        const float bb[4] = {bq.x, bq.y, bq.z, bq.w};
#pragma unroll
        for (int n = 0; n < 2; ++n)
#pragma unroll
            for (int j = 0; j < 4; ++j) pacc[m][n][j] += bb[j];
    }
    __syncthreads();   // all fragment reads done; reuse tile region
#pragma unroll
    for (int n = 0; n < 2; ++n) {
        const int t = ll & 15;
        const int rb = w * 8192 + t * 512;
#pragma unroll
        for (int m = 0; m < 8; ++m) {
            const int ad = rb + (((m * 16 + crow) * 4) ^ ((t & 7) << 4));
            *(f32x4*)(smem + ad) = pacc[m][n];
        }
        asm volatile("s_waitcnt lgkmcnt(0)" ::: "memory");
#pragma unroll
        for (int j = 0; j < 8; ++j) {
            const int fid = j * 64 + ll;
            const int row = fid >> 5;       // 0..15
            const int c4  = fid & 31;
            const int rb3 = w * 8192 + row * 512;
            const f32x4 v = *(f32x4*)(smem + rb3 + ((c4 * 16) ^ ((row & 7) << 4)));
            *(f32x4*)(out + (n0 + w * 32 + n * 16 + row) * 128 + c4 * 4) = v;
        }
    }
}

// ---------------------------------------------------------------------------
extern "C" void kernel_launch(void* const* d_in, const int* in_sizes, int n_in,
                              void* d_out, int out_size, void* d_ws, size_t ws_size,
                              hipStream_t stream)
{
    const float* x       = (const float*)d_in[0];
    const float* Wq      = (const float*)d_in[1];
    const float* Wkv     = (const float*)d_in[2];
    const float* Wproj   = (const float*)d_in[3];
    const float* bproj   = (const float*)d_in[4];
    const float* w_g     = (const float*)d_in[5];
    const float* scale   = (const float*)d_in[6];
    const float* pos_enc = (const float*)d_in[7];
    const float* dwc_w   = (const float*)d_in[8];
    const float* dwc_b   = (const float*)d_in[9];
    float* out = (float*)d_out;

    char* ws = (char*)d_ws;
    unsigned short* qbuf = (unsigned short*)(ws);             // 33554432 B
    unsigned short* kbuf = (unsigned short*)(ws + 33554432);  // 33554432 B
    unsigned short* ktbuf= (unsigned short*)(ws + 67108864);  // 33554432 B
    float* partial = (float*)(ws + 100663296);                // 1052672 B
    float* G       = (float*)(ws + 101715968);                // 4096 B
    float* kbar    = (float*)(ws + 101720064);                // 4096 B
    unsigned short* whi = (unsigned short*)(ws + 101724160);  // 98304 B
    unsigned short* wlo = (unsigned short*)(ws + 101822464);  // 98304 B
    float* sps     = (float*)(ws + 101920768);                // 512 B
    float* zbuf    = (float*)(ws + 101921280);                // 4194304 B

    wprep_kernel<<<dim3(49), dim3(256), 0, stream>>>(
        Wq, Wkv, Wproj, scale, whi, wlo, sps);
    qk_mfma_kernel<<<dim3(1024), dim3(256), 0, stream>>>(
        x, whi, wlo, w_g, sps, pos_enc, qbuf, kbuf, ktbuf, partial);
    reduce_kernel<<<dim3(8), dim3(256), 0, stream>>>(partial, G, kbar);
    z_kernel<<<dim3(2048), dim3(256), 0, stream>>>(qbuf, kbar, zbuf);
    scp_kernel<<<dim3(1024), dim3(256), 0, stream>>>(
        out, kbuf, ktbuf, zbuf, G, whi, wlo, bproj, dwc_w, dwc_b);
}

// Round 16
// 181.013 us; speedup vs baseline: 1.0766x; 1.0766x over previous
//
#include <hip/hip_runtime.h>
#include <hip/hip_bf16.h>

#define BB 8
#define NN 16384
#define CC 128

typedef __attribute__((ext_vector_type(8))) short bf16x8;
typedef __attribute__((ext_vector_type(4))) short short4v;
typedef __attribute__((ext_vector_type(4))) float f32x4;

__device__ __forceinline__ unsigned short f2bf(float f) {
    union { float f; unsigned u; } v; v.f = f;
    unsigned r = v.u + 0x7fffu + ((v.u >> 16) & 1u);
    return (unsigned short)(r >> 16);
}
__device__ __forceinline__ float bf2f(unsigned short h) {
    union { unsigned u; float f; } v; v.u = ((unsigned)h) << 16;
    return v.f;
}
// truncating hi/lo split: lo captures the residual, RNE on hi unnecessary
__device__ __forceinline__ void split_trunc(float f, short& hi, short& lo) {
    union { float f; unsigned u; } v; v.f = f;
    const unsigned short hu = (unsigned short)(v.u >> 16);
    union { unsigned u; float f; } hf; hf.u = ((unsigned)hu) << 16;
    union { float f; unsigned u; } r; r.f = f - hf.f;
    hi = (short)hu;
    lo = (short)(r.u >> 16);
}

// ---------------------------------------------------------------------------
// W prep: split Wq/Wkv/Wproj into bf16 hi/lo (blocks 0-47); block 48
// precomputes sps[c] = 1/softplus(scale[c]). grid 49, block 256.
// ---------------------------------------------------------------------------
__global__ __launch_bounds__(256) void wprep_kernel(
    const float* __restrict__ Wq, const float* __restrict__ Wkv,
    const float* __restrict__ Wp, const float* __restrict__ scale,
    unsigned short* __restrict__ whi, unsigned short* __restrict__ wlo,
    float* __restrict__ sps)
{
    const int bid = blockIdx.x;
    if (bid == 48) {
        if (threadIdx.x < 128)
            sps[threadIdx.x] = 1.f / log1pf(expf(scale[threadIdx.x]));
        return;
    }
    const int mat = bid >> 4;
    const float* src = (mat == 0) ? Wq : ((mat == 1) ? Wkv : Wp);
    const int off = (bid & 15) * 1024 + threadIdx.x * 4;
    const float4 v = *(const float4*)(src + off);
    float f[4] = {v.x, v.y, v.z, v.w};
    short4v hv, lv;
#pragma unroll
    for (int j = 0; j < 4; ++j) {
        short h, lo2;
        split_trunc(f[j], h, lo2);
        hv[j] = h; lv[j] = lo2;
    }
    *(short4v*)(whi + mat * 16384 + off) = hv;
    *(short4v*)(wlo + mat * 16384 + off) = lv;
}

// ---------------------------------------------------------------------------
// qk v10 = R14's qk (W staged in LDS) with token-major kout DELETED:
// its only consumer (scp conv) now reads channel-major k_t. The k
// LDS-transpose phase (2 lgkmcnt drains + 32MB write) is replaced by a
// shuffle ksum (R13-verified lane algebra). WRITE 99->67MB.
// grid 1024, block 256 (4 waves x 32 tokens).
// ---------------------------------------------------------------------------
__global__ __launch_bounds__(256, 1) void qk_mfma_kernel(
    const float* __restrict__ x, const unsigned short* __restrict__ whi,
    const unsigned short* __restrict__ wlo, const float* __restrict__ w_g,
    const float* __restrict__ sps, const float* __restrict__ pos_enc,
    unsigned short* __restrict__ qout, unsigned short* __restrict__ ktout,
    float* __restrict__ partial)
{
    __shared__ __align__(16) char wsm[131072];
    __shared__ float wpart[4][257];
    __shared__ float apl[128];

    const int tid  = threadIdx.x;
    const int w    = tid >> 6;
    const int l    = tid & 63;
    const int blk  = blockIdx.x;
    const int tok0 = blk * 128;
    const int tokb = (blk & 127) * 128;

    bf16x8 xh[2][4], xl[2][4];
#pragma unroll
    for (int n = 0; n < 2; ++n) {
        const int r = w * 32 + n * 16 + (l & 15);
        const float* rowp = x + (tok0 + r) * 128 + (l >> 4) * 8;
#pragma unroll
        for (int kt = 0; kt < 4; ++kt) {
            const f32x4 a = *(const f32x4*)(rowp + kt * 32);
            const f32x4 b = *(const f32x4*)(rowp + kt * 32 + 4);
            const float f[8] = {a[0], a[1], a[2], a[3], b[0], b[1], b[2], b[3]};
            bf16x8 hv, lv;
#pragma unroll
            for (int j = 0; j < 8; ++j) {
                short h, lo2;
                split_trunc(f[j], h, lo2);
                hv[j] = h; lv[j] = lo2;
            }
            xh[n][kt] = hv; xl[n][kt] = lv;
        }
    }

#pragma unroll
    for (int it = 0; it < 32; ++it) {
        const int flat = it * 256 + tid;
        const int arr  = flat >> 11;
        const int c    = (flat >> 4) & 127;
        const int g    = flat & 15;
        const unsigned short* src = ((arr & 1) ? wlo : whi)
                                  + ((arr >> 1) ? 16384 : 0) + c * 128 + g * 8;
        const int dst = arr * 32768 + c * 256 + ((g * 16) ^ ((c & 7) << 4));
        *(bf16x8*)(wsm + dst) = *(const bf16x8*)src;
    }
    __syncthreads();

    const int crow = (l >> 4) * 4;
    f32x4 accq[8][2], acck[8][2];
#pragma unroll
    for (int m = 0; m < 8; ++m)
#pragma unroll
        for (int n = 0; n < 2; ++n) { accq[m][n] = (f32x4)0.f; acck[m][n] = (f32x4)0.f; }

#pragma unroll
    for (int m = 0; m < 8; ++m) {
        const int c = m * 16 + (l & 15);
        const int sw = (c & 7) << 4;
        bf16x8 aqh[4], aql[4], akh[4], akl[4];
#pragma unroll
        for (int kt = 0; kt < 4; ++kt) {
            const int fo = c * 256 + ((kt * 64 + (l >> 4) * 16) ^ sw);
            aqh[kt] = *(const bf16x8*)(wsm + fo);
            aql[kt] = *(const bf16x8*)(wsm + 32768 + fo);
            akh[kt] = *(const bf16x8*)(wsm + 65536 + fo);
            akl[kt] = *(const bf16x8*)(wsm + 98304 + fo);
        }
#pragma unroll
        for (int n = 0; n < 2; ++n)
#pragma unroll
            for (int kt = 0; kt < 4; ++kt) {
                accq[m][n] = __builtin_amdgcn_mfma_f32_16x16x32_bf16(aqh[kt], xh[n][kt], accq[m][n], 0, 0, 0);
                acck[m][n] = __builtin_amdgcn_mfma_f32_16x16x32_bf16(akh[kt], xh[n][kt], acck[m][n], 0, 0, 0);
                accq[m][n] = __builtin_amdgcn_mfma_f32_16x16x32_bf16(aqh[kt], xl[n][kt], accq[m][n], 0, 0, 0);
                acck[m][n] = __builtin_amdgcn_mfma_f32_16x16x32_bf16(akh[kt], xl[n][kt], acck[m][n], 0, 0, 0);
                accq[m][n] = __builtin_amdgcn_mfma_f32_16x16x32_bf16(aql[kt], xh[n][kt], accq[m][n], 0, 0, 0);
                acck[m][n] = __builtin_amdgcn_mfma_f32_16x16x32_bf16(akl[kt], xh[n][kt], acck[m][n], 0, 0, 0);
            }
    }
    __syncthreads();

    // ---- q epilogue (unchanged from R14) ----
    {
#pragma unroll
        for (int m = 0; m < 8; ++m) {
            const float4 is4 = *(const float4*)(sps + m * 16 + crow);
            const float is[4] = {is4.x, is4.y, is4.z, is4.w};
#pragma unroll
            for (int n = 0; n < 2; ++n)
#pragma unroll
                for (int j = 0; j < 4; ++j)
                    accq[m][n][j] = (fmaxf(accq[m][n][j], 0.f) + 1e-6f) * is[j];
        }
        float fqn[2];
#pragma unroll
        for (int n = 0; n < 2; ++n) {
            float s2 = 0.f, s6 = 0.f;
#pragma unroll
            for (int m = 0; m < 8; ++m)
#pragma unroll
                for (int j = 0; j < 4; ++j) {
                    const float v = accq[m][n][j], v2 = v * v;
                    s2 += v2; s6 += v2 * v2 * v2;
                }
            s2 += __shfl_xor(s2, 16); s6 += __shfl_xor(s6, 16);
            s2 += __shfl_xor(s2, 32); s6 += __shfl_xor(s6, 32);
            fqn[n] = sqrtf(s2 / s6);
        }
#pragma unroll
        for (int m = 0; m < 8; ++m)
#pragma unroll
            for (int n = 0; n < 2; ++n)
#pragma unroll
                for (int j = 0; j < 4; ++j) {
                    const float v = accq[m][n][j];
                    accq[m][n][j] = v * v * v * fqn[n];
                }
        float d0 = 0.f, d1 = 0.f;
#pragma unroll
        for (int m = 0; m < 8; ++m) {
            const float4 wgv = *(const float4*)(w_g + m * 16 + crow);
#pragma unroll
            for (int j = 0; j < 4; ++j) {
                const float wg = (j == 0) ? wgv.x : (j == 1) ? wgv.y : (j == 2) ? wgv.z : wgv.w;
                d0 += accq[m][0][j] * wg;
                d1 += accq[m][1][j] * wg;
            }
        }
        d0 += __shfl_xor(d0, 16); d0 += __shfl_xor(d0, 32);
        d1 += __shfl_xor(d1, 16); d1 += __shfl_xor(d1, 32);
        const float ap0 = 0.25f * d0, ap1 = 0.25f * d1;

        float ssa = ap0 * ap0 + ap1 * ap1;
        ssa += __shfl_xor(ssa, 1); ssa += __shfl_xor(ssa, 2);
        ssa += __shfl_xor(ssa, 4); ssa += __shfl_xor(ssa, 8);
        if (l == 0) wpart[w][256] = ssa;
        if (l < 16) { apl[w * 32 + l] = ap0; apl[w * 32 + 16 + l] = ap1; }

        float g4[4] = {0.f, 0.f, 0.f, 0.f};
#pragma unroll
        for (int n = 0; n < 2; ++n) {
            const int t = l & 15;
            const int rb = w * 8192 + t * 512;
#pragma unroll
            for (int m = 0; m < 8; ++m) {
                const int ad = rb + (((m * 16 + crow) * 4) ^ ((t & 7) << 4));
                *(f32x4*)(wsm + ad) = accq[m][n];
            }
            asm volatile("s_waitcnt lgkmcnt(0)" ::: "memory");
#pragma unroll
            for (int j = 0; j < 8; ++j) {
                const int fid = j * 64 + l;
                const int row = fid >> 5;
                const int c4  = fid & 31;
                const int rb3 = w * 8192 + row * 512;
                const f32x4 v = *(f32x4*)(wsm + rb3 + ((c4 * 16) ^ ((row & 7) << 4)));
                const float apv = apl[w * 32 + n * 16 + row];
                short4v qv;
#pragma unroll
                for (int i = 0; i < 4; ++i) {
                    g4[i] += apv * v[i];
                    qv[i] = (short)f2bf(v[i]);
                }
                *(short4v*)(qout + (tok0 + w * 32 + n * 16 + row) * 128 + c4 * 4) = qv;
            }
        }
#pragma unroll
        for (int i = 0; i < 4; ++i) g4[i] += __shfl_xor(g4[i], 32);
        if (l < 32) {
#pragma unroll
            for (int i = 0; i < 4; ++i) wpart[w][(l & 31) * 4 + i] = g4[i];
        }
    }

    // ---- k epilogue: act(+pos) + focusing; ksum via SHUFFLES (no kout) ----
    {
#pragma unroll
        for (int m = 0; m < 8; ++m) {
            const float4 is4 = *(const float4*)(sps + m * 16 + crow);
            const float is[4] = {is4.x, is4.y, is4.z, is4.w};
#pragma unroll
            for (int n = 0; n < 2; ++n) {
                const int t = tokb + w * 32 + n * 16 + (l & 15);
                const float4 p = *(const float4*)(pos_enc + t * 128 + m * 16 + crow);
                const float pe[4] = {p.x, p.y, p.z, p.w};
#pragma unroll
                for (int j = 0; j < 4; ++j)
                    acck[m][n][j] = (fmaxf(acck[m][n][j] + pe[j], 0.f) + 1e-6f) * is[j];
            }
        }
        float fkn[2];
#pragma unroll
        for (int n = 0; n < 2; ++n) {
            float s2 = 0.f, s6 = 0.f;
#pragma unroll
            for (int m = 0; m < 8; ++m)
#pragma unroll
                for (int j = 0; j < 4; ++j) {
                    const float v = acck[m][n][j], v2 = v * v;
                    s2 += v2; s6 += v2 * v2 * v2;
                }
            s2 += __shfl_xor(s2, 16); s6 += __shfl_xor(s6, 16);
            s2 += __shfl_xor(s2, 32); s6 += __shfl_xor(s6, 32);
            fkn[n] = sqrtf(s2 / s6);
        }
#pragma unroll
        for (int m = 0; m < 8; ++m)
#pragma unroll
            for (int n = 0; n < 2; ++n)
#pragma unroll
                for (int j = 0; j < 4; ++j) {
                    const float v = acck[m][n][j];
                    acck[m][n][j] = v * v * v * fkn[n];
                }
        // ksum partial per channel: sum over this wave's 32 tokens
#pragma unroll
        for (int m = 0; m < 8; ++m)
#pragma unroll
            for (int j = 0; j < 4; ++j) {
                float s = acck[m][0][j] + acck[m][1][j];
                s += __shfl_xor(s, 1); s += __shfl_xor(s, 2);
                s += __shfl_xor(s, 4); s += __shfl_xor(s, 8);
                if ((l & 15) == 0) wpart[w][128 + m * 16 + crow + j] = s;
            }
    }

    // ---- k_t (channel-major) via block LDS scatter (reused region) ----
    __syncthreads();
#pragma unroll
    for (int m = 0; m < 8; ++m)
#pragma unroll
        for (int n = 0; n < 2; ++n)
#pragma unroll
            for (int j = 0; j < 4; ++j) {
                const int ch = m * 16 + crow + j;
                const int tl = w * 32 + n * 16 + (l & 15);
                *(unsigned short*)(wsm + ch * 264 + tl * 2) = f2bf(acck[m][n][j]);
            }
    __syncthreads();
    {
        const int bb = blk >> 7;
        unsigned* ktp = (unsigned*)ktout;
#pragma unroll
        for (int it = 0; it < 32; ++it) {
            const int idx = it * 256 + tid;
            const int row = idx >> 6;
            const int col = idx & 63;
            const unsigned v = *(unsigned*)(wsm + row * 264 + col * 4);
            ktp[(size_t)(bb * 128 + row) * 8192 + (blk & 127) * 64 + col] = v;
        }
    }

    __syncthreads();
    float* pblk = partial + blk * 257;
    if (tid < 128) {
        pblk[tid] = wpart[0][tid] + wpart[1][tid] + wpart[2][tid] + wpart[3][tid];
        pblk[128 + tid] = wpart[0][128 + tid] + wpart[1][128 + tid] +
                          wpart[2][128 + tid] + wpart[3][128 + tid];
    } else if (tid == 128) {
        pblk[256] = wpart[0][256] + wpart[1][256] + wpart[2][256] + wpart[3][256];
    }
}

// ---------------------------------------------------------------------------
// reduce partials -> G, kbar. grid 8, block 256.
// ---------------------------------------------------------------------------
__global__ __launch_bounds__(256) void reduce_kernel(
    const float* __restrict__ partial, float* __restrict__ G,
    float* __restrict__ kbar)
{
    const int b = blockIdx.x;
    const int tid = threadIdx.x;
    __shared__ float tmp[4];

    float ssa = (tid < 128) ? partial[(b * 128 + tid) * 257 + 256] : 0.f;
#pragma unroll
    for (int o = 32; o >= 1; o >>= 1) ssa += __shfl_xor(ssa, o);
    if ((tid & 63) == 0) tmp[tid >> 6] = ssa;
    __syncthreads();
    const float anorm = fmaxf(sqrtf(tmp[0] + tmp[1] + tmp[2] + tmp[3]), 1e-12f);
    const float inv_a = 1.f / anorm;

    if (tid < 128) {
        float g = 0.f;
        for (int t = 0; t < 128; ++t)
            g += partial[(b * 128 + t) * 257 + tid];
        G[b * 128 + tid] = g * inv_a;
    } else {
        const int c2 = tid - 128;
        float s = 0.f;
        for (int t = 0; t < 128; ++t)
            s += partial[(b * 128 + t) * 257 + 128 + c2];
        kbar[b * 128 + c2] = s * (1.f / 16384.f);
    }
}

// ---------------------------------------------------------------------------
// z kernel. grid 2048, block 256.
// ---------------------------------------------------------------------------
__global__ __launch_bounds__(256) void z_kernel(
    const unsigned short* __restrict__ q, const float* __restrict__ kbar,
    float* __restrict__ z)
{
    const int bid = blockIdx.x;
    const int b   = bid >> 8;
    const int tg  = bid & 255;
    const int tid = threadIdx.x;
    const int t   = tid >> 2;
    const int qt  = tid & 3;
    const int tok = tg * 64 + t;

    const unsigned short* qp = q + ((size_t)b * NN + tok) * 128 + qt * 32;
    const float* kb = kbar + b * 128 + qt * 32;

    float dot0 = 0.f, dot1 = 0.f;
#pragma unroll
    for (int c = 0; c < 4; ++c) {
        const short4v q4a = *(const short4v*)(qp + c * 8);
        const short4v q4b = *(const short4v*)(qp + c * 8 + 4);
        const float4 k4a = *(const float4*)(kb + c * 8);
        const float4 k4b = *(const float4*)(kb + c * 8 + 4);
        float d = bf2f((unsigned short)q4a[0]) * k4a.x + bf2f((unsigned short)q4a[1]) * k4a.y +
                  bf2f((unsigned short)q4a[2]) * k4a.z + bf2f((unsigned short)q4a[3]) * k4a.w +
                  bf2f((unsigned short)q4b[0]) * k4b.x + bf2f((unsigned short)q4b[1]) * k4b.y +
                  bf2f((unsigned short)q4b[2]) * k4b.z + bf2f((unsigned short)q4b[3]) * k4b.w;
        if (c < 2) dot0 += d; else dot1 += d;
    }
    z[((size_t)b * 8 + qt * 2) * NN + tok]     = 1.f / (dot0 + 1e-6f);
    z[((size_t)b * 8 + qt * 2 + 1) * NN + tok] = 1.f / (dot1 + 1e-6f);
}

// ---------------------------------------------------------------------------
// scp v4: conv reads CHANNEL-MAJOR k_t (R13-verified code; token-major kbuf
// deleted program-wide), single-bf16 proj tile (R15). u-part from k_t + z.
// Batch-per-XCD swizzle. grid 1024, block 256.
// ---------------------------------------------------------------------------
__global__ __launch_bounds__(256, 2) void scp_kernel(
    float* __restrict__ out, const unsigned short* __restrict__ kt,
    const float* __restrict__ z, const float* __restrict__ G,
    const unsigned short* __restrict__ whi, const unsigned short* __restrict__ wlo,
    const float* __restrict__ bp, const float* __restrict__ dwc_w,
    const float* __restrict__ dwc_b)
{
    __shared__ __align__(16) char smem[32768];   // single-bf16 tile / transpose
    __shared__ float wct[25][16];
    __shared__ float bi[16];
    __shared__ float Gs;

    const int tid  = threadIdx.x;
    const int bid0 = blockIdx.x;
    const int bid  = (bid0 & 7) * 128 + (bid0 >> 3);   // bijective XCD swizzle
    const int cc   = bid & 127;
    const int b    = bid >> 7;
    const int n0   = bid * 128;

    for (int i = tid; i < 400; i += 256)
        wct[i >> 4][i & 15] = dwc_w[(i & 15) * 25 + (i >> 4)];
    if (tid < 16) bi[tid] = dwc_b[tid];
    if (tid == 0) Gs = G[b * 128 + cc];
    __syncthreads();

    const int ch4 = tid >> 3;         // channel quad 0..31
    const int xg  = tid & 7;          // x-group 0..7

    float acc[4][16];
#pragma unroll
    for (int c = 0; c < 4; ++c)
#pragma unroll
        for (int i = 0; i < 16; ++i) acc[c][i] = 0.f;

#pragma unroll
    for (int dy = 0; dy < 5; ++dy) {
        const int yy = cc + dy - 2;
        if (yy < 0 || yy > 127) continue;
#pragma unroll
        for (int c = 0; c < 4; ++c) {
            const int ch = ch4 * 4 + c;
            const unsigned short* rowp = kt + ((size_t)b * 128 + ch) * NN
                                            + yy * 128 + xg * 16 - 8;
            float wf[32];
#pragma unroll
            for (int q4 = 0; q4 < 4; ++q4) {
                const bf16x8 v = *(const bf16x8*)(rowp + q4 * 8);
#pragma unroll
                for (int e = 0; e < 8; ++e)
                    wf[q4 * 8 + e] = bf2f((unsigned short)v[e]);
            }
            if (xg == 0) {
#pragma unroll
                for (int e = 0; e < 8; ++e) wf[e] = 0.f;
            }
            if (xg == 7) {
#pragma unroll
                for (int e = 24; e < 32; ++e) wf[e] = 0.f;
            }
            const int d = ch & 15;
#pragma unroll
            for (int dx = 0; dx < 5; ++dx) {
                const float wv = wct[dy * 5 + dx][d];
#pragma unroll
                for (int i = 0; i < 16; ++i)
                    acc[c][i] += wv * wf[i + dx + 6];
            }
        }
    }

    // ---- phase 2: u-part inline + conv + bias -> single-bf16 tile ----
    const float Gcc = Gs;
    const unsigned short* kub = kt + ((size_t)b * 128 + cc) * NN;
    const float* zr = z + ((size_t)b * 8 + (cc >> 4)) * NN;
    const int dbase = (ch4 & 3) * 4;
    const float4 b4 = *(const float4*)(&bi[dbase]);
    const float bv[4] = {b4.x, b4.y, b4.z, b4.w};
#pragma unroll
    for (int i = 0; i < 16; ++i) {
        const int r = xg * 16 + i;
        const int toks = r * 128 + ch4 * 4;
        const short4v ku4 = *(const short4v*)(kub + toks);
        const float4 z4 = *(const float4*)(zr + toks);
        const float zz[4] = {z4.x, z4.y, z4.z, z4.w};
        short4v hv;
#pragma unroll
        for (int c = 0; c < 4; ++c) {
            const float f = Gcc * bf2f((unsigned short)ku4[c]) * zz[c] + acc[c][i] + bv[c];
            hv[c] = (short)f2bf(f);
        }
        const int ad = r * 256 + (((ch4 >> 1) * 16) ^ ((r & 7) << 4)) + (ch4 & 1) * 8;
        *(short4v*)(smem + ad) = hv;
    }
    __syncthreads();

    // ---- proj MFMA (A = Wproj hi/lo from L2, B = single-bf16 tile) ----
    const int w  = tid >> 6;
    const int ll = tid & 63;
    bf16x8 xh[2][4];
    {
        const int lg16 = (ll >> 4) * 16;
#pragma unroll
        for (int n = 0; n < 2; ++n) {
            const int r = w * 32 + n * 16 + (ll & 15);
            const int rb = r * 256;
            const int sw = (r & 7) << 4;
#pragma unroll
            for (int kt2 = 0; kt2 < 4; ++kt2)
                xh[n][kt2] = *(bf16x8*)(smem + rb + ((kt2 * 64 + lg16) ^ sw));
        }
    }
    const int crow = (ll >> 4) * 4;
    f32x4 pacc[8][2];
#pragma unroll
    for (int m = 0; m < 8; ++m)
#pragma unroll
        for (int n = 0; n < 2; ++n) pacc[m][n] = (f32x4)0.f;

#pragma unroll
    for (int m = 0; m < 8; ++m) {
        const int c = m * 16 + (ll & 15);
        bf16x8 ah[4], al[4];
#pragma unroll
        for (int kt2 = 0; kt2 < 4; ++kt2) {
            const int off = 32768 + c * 128 + kt2 * 32 + (ll >> 4) * 8;
            ah[kt2] = *(const bf16x8*)(whi + off);
            al[kt2] = *(const bf16x8*)(wlo + off);
        }
#pragma unroll
        for (int n = 0; n < 2; ++n)
#pragma unroll
            for (int kt2 = 0; kt2 < 4; ++kt2) {
                pacc[m][n] = __builtin_amdgcn_mfma_f32_16x16x32_bf16(ah[kt2], xh[n][kt2], pacc[m][n], 0, 0, 0);
                pacc[m][n] = __builtin_amdgcn_mfma_f32_16x16x32_bf16(al[kt2], xh[n][kt2], pacc[m][n], 0, 0, 0);
            }
    }

    // ---- bias + transpose (wave-private 8KB, two sub-phases) + store ----
#pragma unroll
    for (int m = 0; m < 8; ++m) {
        const float4 bq = *(const float4*)(bp + m * 16 + crow);
        const float bb[4] = {bq.x, bq.y, bq.z, bq.w};
#pragma unroll
        for (int n = 0; n < 2; ++n)
#pragma unroll
            for (int j = 0; j < 4; ++j) pacc[m][n][j] += bb[j];
    }
    __syncthreads();
#pragma unroll
    for (int n = 0; n < 2; ++n) {
        const int t = ll & 15;
        const int rb = w * 8192 + t * 512;
#pragma unroll
        for (int m = 0; m < 8; ++m) {
            const int ad = rb + (((m * 16 + crow) * 4) ^ ((t & 7) << 4));
            *(f32x4*)(smem + ad) = pacc[m][n];
        }
        asm volatile("s_waitcnt lgkmcnt(0)" ::: "memory");
#pragma unroll
        for (int j = 0; j < 8; ++j) {
            const int fid = j * 64 + ll;
            const int row = fid >> 5;
            const int c4  = fid & 31;
            const int rb3 = w * 8192 + row * 512;
            const f32x4 v = *(f32x4*)(smem + rb3 + ((c4 * 16) ^ ((row & 7) << 4)));
            *(f32x4*)(out + (n0 + w * 32 + n * 16 + row) * 128 + c4 * 4) = v;
        }
    }
}

// ---------------------------------------------------------------------------
extern "C" void kernel_launch(void* const* d_in, const int* in_sizes, int n_in,
                              void* d_out, int out_size, void* d_ws, size_t ws_size,
                              hipStream_t stream)
{
    const float* x       = (const float*)d_in[0];
    const float* Wq      = (const float*)d_in[1];
    const float* Wkv     = (const float*)d_in[2];
    const float* Wproj   = (const float*)d_in[3];
    const float* bproj   = (const float*)d_in[4];
    const float* w_g     = (const float*)d_in[5];
    const float* scale   = (const float*)d_in[6];
    const float* pos_enc = (const float*)d_in[7];
    const float* dwc_w   = (const float*)d_in[8];
    const float* dwc_b   = (const float*)d_in[9];
    float* out = (float*)d_out;

    char* ws = (char*)d_ws;
    unsigned short* qbuf = (unsigned short*)(ws);             // 33554432 B
    unsigned short* ktbuf= (unsigned short*)(ws + 33554432);  // 33554432 B
    float* partial = (float*)(ws + 67108864);                 // 1052672 B
    float* G       = (float*)(ws + 68161536);                 // 4096 B
    float* kbar    = (float*)(ws + 68165632);                 // 4096 B
    unsigned short* whi = (unsigned short*)(ws + 68169728);   // 98304 B
    unsigned short* wlo = (unsigned short*)(ws + 68268032);   // 98304 B
    float* sps     = (float*)(ws + 68366336);                 // 512 B
    float* zbuf    = (float*)(ws + 68366848);                 // 4194304 B

    wprep_kernel<<<dim3(49), dim3(256), 0, stream>>>(
        Wq, Wkv, Wproj, scale, whi, wlo, sps);
    qk_mfma_kernel<<<dim3(1024), dim3(256), 0, stream>>>(
        x, whi, wlo, w_g, sps, pos_enc, qbuf, ktbuf, partial);
    reduce_kernel<<<dim3(8), dim3(256), 0, stream>>>(partial, G, kbar);
    z_kernel<<<dim3(2048), dim3(256), 0, stream>>>(qbuf, kbar, zbuf);
    scp_kernel<<<dim3(1024), dim3(256), 0, stream>>>(
        out, ktbuf, zbuf, G, whi, wlo, bproj, dwc_w, dwc_b);
}

// Round 17
// 169.439 us; speedup vs baseline: 1.1501x; 1.0683x over previous
//
#include <hip/hip_runtime.h>
#include <hip/hip_bf16.h>

#define BB 8
#define NN 16384
#define CC 128

typedef __attribute__((ext_vector_type(8))) short bf16x8;
typedef __attribute__((ext_vector_type(4))) short short4v;
typedef __attribute__((ext_vector_type(4))) float f32x4;

__device__ __forceinline__ unsigned short f2bf(float f) {
    union { float f; unsigned u; } v; v.f = f;
    unsigned r = v.u + 0x7fffu + ((v.u >> 16) & 1u);
    return (unsigned short)(r >> 16);
}
__device__ __forceinline__ float bf2f(unsigned short h) {
    union { unsigned u; float f; } v; v.u = ((unsigned)h) << 16;
    return v.f;
}
// truncating hi/lo split: lo captures the residual, RNE on hi unnecessary
__device__ __forceinline__ void split_trunc(float f, short& hi, short& lo) {
    union { float f; unsigned u; } v; v.f = f;
    const unsigned short hu = (unsigned short)(v.u >> 16);
    union { unsigned u; float f; } hf; hf.u = ((unsigned)hu) << 16;
    union { float f; unsigned u; } r; r.f = f - hf.f;
    hi = (short)hu;
    lo = (short)(r.u >> 16);
}

// ---------------------------------------------------------------------------
// W prep: split Wq/Wkv/Wproj into bf16 hi/lo (blocks 0-47); block 48
// precomputes sps[c] = 1/softplus(scale[c]). grid 49, block 256.
// ---------------------------------------------------------------------------
__global__ __launch_bounds__(256) void wprep_kernel(
    const float* __restrict__ Wq, const float* __restrict__ Wkv,
    const float* __restrict__ Wp, const float* __restrict__ scale,
    unsigned short* __restrict__ whi, unsigned short* __restrict__ wlo,
    float* __restrict__ sps)
{
    const int bid = blockIdx.x;
    if (bid == 48) {
        if (threadIdx.x < 128)
            sps[threadIdx.x] = 1.f / log1pf(expf(scale[threadIdx.x]));
        return;
    }
    const int mat = bid >> 4;
    const float* src = (mat == 0) ? Wq : ((mat == 1) ? Wkv : Wp);
    const int off = (bid & 15) * 1024 + threadIdx.x * 4;
    const float4 v = *(const float4*)(src + off);
    float f[4] = {v.x, v.y, v.z, v.w};
    short4v hv, lv;
#pragma unroll
    for (int j = 0; j < 4; ++j) {
        short h, lo2;
        split_trunc(f[j], h, lo2);
        hv[j] = h; lv[j] = lo2;
    }
    *(short4v*)(whi + mat * 16384 + off) = hv;
    *(short4v*)(wlo + mat * 16384 + off) = lv;
}

// ---------------------------------------------------------------------------
// qproj: x @ Wq.T + focusing -> qout (bf16) + ap/ssa/G partials.
// Split from R16's fused qk (136KB LDS, 180 VGPR -> 1 block/CU, 1 wave/SIMD,
// occ 10.5%): each half stages only its 2 W arrays (64KB) and holds one
// 64-reg accumulator set -> 2 blocks/CU + 2 waves/SIMD. x re-read is the
// price (+64MB at 15% HBM util — cheap). grid 1024, block 256.
// ---------------------------------------------------------------------------
__global__ __launch_bounds__(256, 2) void qproj_kernel(
    const float* __restrict__ x, const unsigned short* __restrict__ whi,
    const unsigned short* __restrict__ wlo, const float* __restrict__ w_g,
    const float* __restrict__ sps,
    unsigned short* __restrict__ qout, float* __restrict__ partial1)
{
    __shared__ __align__(16) char wsm[65536];   // Wq hi [0,32K) lo [32K,64K); reused
    __shared__ float wpart[4][132];
    __shared__ float apl[128];

    const int tid  = threadIdx.x;
    const int w    = tid >> 6;
    const int l    = tid & 63;
    const int blk  = blockIdx.x;
    const int tok0 = blk * 128;

    bf16x8 xh[2][4], xl[2][4];
#pragma unroll
    for (int n = 0; n < 2; ++n) {
        const int r = w * 32 + n * 16 + (l & 15);
        const float* rowp = x + (tok0 + r) * 128 + (l >> 4) * 8;
#pragma unroll
        for (int kt = 0; kt < 4; ++kt) {
            const f32x4 a = *(const f32x4*)(rowp + kt * 32);
            const f32x4 b = *(const f32x4*)(rowp + kt * 32 + 4);
            const float f[8] = {a[0], a[1], a[2], a[3], b[0], b[1], b[2], b[3]};
            bf16x8 hv, lv;
#pragma unroll
            for (int j = 0; j < 8; ++j) {
                short h, lo2;
                split_trunc(f[j], h, lo2);
                hv[j] = h; lv[j] = lo2;
            }
            xh[n][kt] = hv; xl[n][kt] = lv;
        }
    }

    // stage Wq hi+lo (4096 chunks of 16B)
#pragma unroll
    for (int it = 0; it < 16; ++it) {
        const int flat = it * 256 + tid;
        const int arr  = flat >> 11;              // 0=hi 1=lo
        const int c    = (flat >> 4) & 127;
        const int g    = flat & 15;
        const unsigned short* src = (arr ? wlo : whi) + c * 128 + g * 8;
        const int dst = arr * 32768 + c * 256 + ((g * 16) ^ ((c & 7) << 4));
        *(bf16x8*)(wsm + dst) = *(const bf16x8*)src;
    }
    __syncthreads();

    const int crow = (l >> 4) * 4;
    f32x4 acc[8][2];
#pragma unroll
    for (int m = 0; m < 8; ++m)
#pragma unroll
        for (int n = 0; n < 2; ++n) acc[m][n] = (f32x4)0.f;

#pragma unroll
    for (int m = 0; m < 8; ++m) {
        const int c = m * 16 + (l & 15);
        const int sw = (c & 7) << 4;
        bf16x8 ah[4], al[4];
#pragma unroll
        for (int kt = 0; kt < 4; ++kt) {
            const int fo = c * 256 + ((kt * 64 + (l >> 4) * 16) ^ sw);
            ah[kt] = *(const bf16x8*)(wsm + fo);
            al[kt] = *(const bf16x8*)(wsm + 32768 + fo);
        }
#pragma unroll
        for (int n = 0; n < 2; ++n)
#pragma unroll
            for (int kt = 0; kt < 4; ++kt) {
                acc[m][n] = __builtin_amdgcn_mfma_f32_16x16x32_bf16(ah[kt], xh[n][kt], acc[m][n], 0, 0, 0);
                acc[m][n] = __builtin_amdgcn_mfma_f32_16x16x32_bf16(ah[kt], xl[n][kt], acc[m][n], 0, 0, 0);
                acc[m][n] = __builtin_amdgcn_mfma_f32_16x16x32_bf16(al[kt], xh[n][kt], acc[m][n], 0, 0, 0);
            }
    }
    __syncthreads();   // W region dead; reuse for transpose

    // ---- epilogue: act + focusing + ap/ssa/G + transposed bf16 store ----
#pragma unroll
    for (int m = 0; m < 8; ++m) {
        const float4 is4 = *(const float4*)(sps + m * 16 + crow);
        const float is[4] = {is4.x, is4.y, is4.z, is4.w};
#pragma unroll
        for (int n = 0; n < 2; ++n)
#pragma unroll
            for (int j = 0; j < 4; ++j)
                acc[m][n][j] = (fmaxf(acc[m][n][j], 0.f) + 1e-6f) * is[j];
    }
    float fqn[2];
#pragma unroll
    for (int n = 0; n < 2; ++n) {
        float s2 = 0.f, s6 = 0.f;
#pragma unroll
        for (int m = 0; m < 8; ++m)
#pragma unroll
            for (int j = 0; j < 4; ++j) {
                const float v = acc[m][n][j], v2 = v * v;
                s2 += v2; s6 += v2 * v2 * v2;
            }
        s2 += __shfl_xor(s2, 16); s6 += __shfl_xor(s6, 16);
        s2 += __shfl_xor(s2, 32); s6 += __shfl_xor(s6, 32);
        fqn[n] = sqrtf(s2 / s6);
    }
#pragma unroll
    for (int m = 0; m < 8; ++m)
#pragma unroll
        for (int n = 0; n < 2; ++n)
#pragma unroll
            for (int j = 0; j < 4; ++j) {
                const float v = acc[m][n][j];
                acc[m][n][j] = v * v * v * fqn[n];
            }
    float d0 = 0.f, d1 = 0.f;
#pragma unroll
    for (int m = 0; m < 8; ++m) {
        const float4 wgv = *(const float4*)(w_g + m * 16 + crow);
#pragma unroll
        for (int j = 0; j < 4; ++j) {
            const float wg = (j == 0) ? wgv.x : (j == 1) ? wgv.y : (j == 2) ? wgv.z : wgv.w;
            d0 += acc[m][0][j] * wg;
            d1 += acc[m][1][j] * wg;
        }
    }
    d0 += __shfl_xor(d0, 16); d0 += __shfl_xor(d0, 32);
    d1 += __shfl_xor(d1, 16); d1 += __shfl_xor(d1, 32);
    const float ap0 = 0.25f * d0, ap1 = 0.25f * d1;

    float ssa = ap0 * ap0 + ap1 * ap1;
    ssa += __shfl_xor(ssa, 1); ssa += __shfl_xor(ssa, 2);
    ssa += __shfl_xor(ssa, 4); ssa += __shfl_xor(ssa, 8);
    if (l == 0) wpart[w][128] = ssa;
    if (l < 16) { apl[w * 32 + l] = ap0; apl[w * 32 + 16 + l] = ap1; }

    float g4[4] = {0.f, 0.f, 0.f, 0.f};
#pragma unroll
    for (int n = 0; n < 2; ++n) {
        const int t = l & 15;
        const int rb = w * 8192 + t * 512;
#pragma unroll
        for (int m = 0; m < 8; ++m) {
            const int ad = rb + (((m * 16 + crow) * 4) ^ ((t & 7) << 4));
            *(f32x4*)(wsm + ad) = acc[m][n];
        }
        asm volatile("s_waitcnt lgkmcnt(0)" ::: "memory");
#pragma unroll
        for (int j = 0; j < 8; ++j) {
            const int fid = j * 64 + l;
            const int row = fid >> 5;
            const int c4  = fid & 31;
            const int rb3 = w * 8192 + row * 512;
            const f32x4 v = *(f32x4*)(wsm + rb3 + ((c4 * 16) ^ ((row & 7) << 4)));
            const float apv = apl[w * 32 + n * 16 + row];
            short4v qv;
#pragma unroll
            for (int i = 0; i < 4; ++i) {
                g4[i] += apv * v[i];
                qv[i] = (short)f2bf(v[i]);
            }
            *(short4v*)(qout + (tok0 + w * 32 + n * 16 + row) * 128 + c4 * 4) = qv;
        }
    }
#pragma unroll
    for (int i = 0; i < 4; ++i) g4[i] += __shfl_xor(g4[i], 32);
    if (l < 32) {
#pragma unroll
        for (int i = 0; i < 4; ++i) wpart[w][(l & 31) * 4 + i] = g4[i];
    }
    __syncthreads();
    float* pblk = partial1 + blk * 132;
    if (tid < 128)
        pblk[tid] = wpart[0][tid] + wpart[1][tid] + wpart[2][tid] + wpart[3][tid];
    else if (tid == 128)
        pblk[128] = wpart[0][128] + wpart[1][128] + wpart[2][128] + wpart[3][128];
}

// ---------------------------------------------------------------------------
// kproj: x @ Wkv.T + pos_enc + focusing -> k_t (channel-major bf16) + ksum.
// grid 1024, block 256.
// ---------------------------------------------------------------------------
__global__ __launch_bounds__(256, 2) void kproj_kernel(
    const float* __restrict__ x, const unsigned short* __restrict__ whi,
    const unsigned short* __restrict__ wlo,
    const float* __restrict__ sps, const float* __restrict__ pos_enc,
    unsigned short* __restrict__ ktout, float* __restrict__ partial2)
{
    __shared__ __align__(16) char wsm[65536];   // Wk hi/lo; reused for k_t scatter
    __shared__ float wpart[4][128];

    const int tid  = threadIdx.x;
    const int w    = tid >> 6;
    const int l    = tid & 63;
    const int blk  = blockIdx.x;
    const int tok0 = blk * 128;
    const int tokb = (blk & 127) * 128;

    bf16x8 xh[2][4], xl[2][4];
#pragma unroll
    for (int n = 0; n < 2; ++n) {
        const int r = w * 32 + n * 16 + (l & 15);
        const float* rowp = x + (tok0 + r) * 128 + (l >> 4) * 8;
#pragma unroll
        for (int kt = 0; kt < 4; ++kt) {
            const f32x4 a = *(const f32x4*)(rowp + kt * 32);
            const f32x4 b = *(const f32x4*)(rowp + kt * 32 + 4);
            const float f[8] = {a[0], a[1], a[2], a[3], b[0], b[1], b[2], b[3]};
            bf16x8 hv, lv;
#pragma unroll
            for (int j = 0; j < 8; ++j) {
                short h, lo2;
                split_trunc(f[j], h, lo2);
                hv[j] = h; lv[j] = lo2;
            }
            xh[n][kt] = hv; xl[n][kt] = lv;
        }
    }

    // stage Wk hi+lo (offset 16384 in whi/wlo)
#pragma unroll
    for (int it = 0; it < 16; ++it) {
        const int flat = it * 256 + tid;
        const int arr  = flat >> 11;
        const int c    = (flat >> 4) & 127;
        const int g    = flat & 15;
        const unsigned short* src = (arr ? wlo : whi) + 16384 + c * 128 + g * 8;
        const int dst = arr * 32768 + c * 256 + ((g * 16) ^ ((c & 7) << 4));
        *(bf16x8*)(wsm + dst) = *(const bf16x8*)src;
    }
    __syncthreads();

    const int crow = (l >> 4) * 4;
    f32x4 acc[8][2];
#pragma unroll
    for (int m = 0; m < 8; ++m)
#pragma unroll
        for (int n = 0; n < 2; ++n) acc[m][n] = (f32x4)0.f;

#pragma unroll
    for (int m = 0; m < 8; ++m) {
        const int c = m * 16 + (l & 15);
        const int sw = (c & 7) << 4;
        bf16x8 ah[4], al[4];
#pragma unroll
        for (int kt = 0; kt < 4; ++kt) {
            const int fo = c * 256 + ((kt * 64 + (l >> 4) * 16) ^ sw);
            ah[kt] = *(const bf16x8*)(wsm + fo);
            al[kt] = *(const bf16x8*)(wsm + 32768 + fo);
        }
#pragma unroll
        for (int n = 0; n < 2; ++n)
#pragma unroll
            for (int kt = 0; kt < 4; ++kt) {
                acc[m][n] = __builtin_amdgcn_mfma_f32_16x16x32_bf16(ah[kt], xh[n][kt], acc[m][n], 0, 0, 0);
                acc[m][n] = __builtin_amdgcn_mfma_f32_16x16x32_bf16(ah[kt], xl[n][kt], acc[m][n], 0, 0, 0);
                acc[m][n] = __builtin_amdgcn_mfma_f32_16x16x32_bf16(al[kt], xh[n][kt], acc[m][n], 0, 0, 0);
            }
    }
    __syncthreads();   // W region dead; reuse for k_t scatter

    // ---- epilogue: act(+pos) + focusing + ksum + k_t scatter ----
#pragma unroll
    for (int m = 0; m < 8; ++m) {
        const float4 is4 = *(const float4*)(sps + m * 16 + crow);
        const float is[4] = {is4.x, is4.y, is4.z, is4.w};
#pragma unroll
        for (int n = 0; n < 2; ++n) {
            const int t = tokb + w * 32 + n * 16 + (l & 15);
            const float4 p = *(const float4*)(pos_enc + t * 128 + m * 16 + crow);
            const float pe[4] = {p.x, p.y, p.z, p.w};
#pragma unroll
            for (int j = 0; j < 4; ++j)
                acc[m][n][j] = (fmaxf(acc[m][n][j] + pe[j], 0.f) + 1e-6f) * is[j];
        }
    }
    float fkn[2];
#pragma unroll
    for (int n = 0; n < 2; ++n) {
        float s2 = 0.f, s6 = 0.f;
#pragma unroll
        for (int m = 0; m < 8; ++m)
#pragma unroll
            for (int j = 0; j < 4; ++j) {
                const float v = acc[m][n][j], v2 = v * v;
                s2 += v2; s6 += v2 * v2 * v2;
            }
        s2 += __shfl_xor(s2, 16); s6 += __shfl_xor(s6, 16);
        s2 += __shfl_xor(s2, 32); s6 += __shfl_xor(s6, 32);
        fkn[n] = sqrtf(s2 / s6);
    }
#pragma unroll
    for (int m = 0; m < 8; ++m)
#pragma unroll
        for (int n = 0; n < 2; ++n)
#pragma unroll
            for (int j = 0; j < 4; ++j) {
                const float v = acc[m][n][j];
                acc[m][n][j] = v * v * v * fkn[n];
            }
#pragma unroll
    for (int m = 0; m < 8; ++m)
#pragma unroll
        for (int j = 0; j < 4; ++j) {
            float s = acc[m][0][j] + acc[m][1][j];
            s += __shfl_xor(s, 1); s += __shfl_xor(s, 2);
            s += __shfl_xor(s, 4); s += __shfl_xor(s, 8);
            if ((l & 15) == 0) wpart[w][m * 16 + crow + j] = s;
        }

    // k_t scatter via reused LDS ([128][264B])
#pragma unroll
    for (int m = 0; m < 8; ++m)
#pragma unroll
        for (int n = 0; n < 2; ++n)
#pragma unroll
            for (int j = 0; j < 4; ++j) {
                const int ch = m * 16 + crow + j;
                const int tl = w * 32 + n * 16 + (l & 15);
                *(unsigned short*)(wsm + ch * 264 + tl * 2) = f2bf(acc[m][n][j]);
            }
    __syncthreads();
    {
        const int bb = blk >> 7;
        unsigned* ktp = (unsigned*)ktout;
#pragma unroll
        for (int it = 0; it < 32; ++it) {
            const int idx = it * 256 + tid;
            const int row = idx >> 6;
            const int col = idx & 63;
            const unsigned v = *(unsigned*)(wsm + row * 264 + col * 4);
            ktp[(size_t)(bb * 128 + row) * 8192 + (blk & 127) * 64 + col] = v;
        }
    }
    __syncthreads();
    if (tid < 128)
        partial2[blk * 128 + tid] = wpart[0][tid] + wpart[1][tid] +
                                    wpart[2][tid] + wpart[3][tid];
}

// ---------------------------------------------------------------------------
// reduce: G from partial1 (+ssa), kbar from partial2. grid 8, block 256.
// ---------------------------------------------------------------------------
__global__ __launch_bounds__(256) void reduce_kernel(
    const float* __restrict__ partial1, const float* __restrict__ partial2,
    float* __restrict__ G, float* __restrict__ kbar)
{
    const int b = blockIdx.x;
    const int tid = threadIdx.x;
    __shared__ float tmp[4];

    float ssa = (tid < 128) ? partial1[(b * 128 + tid) * 132 + 128] : 0.f;
#pragma unroll
    for (int o = 32; o >= 1; o >>= 1) ssa += __shfl_xor(ssa, o);
    if ((tid & 63) == 0) tmp[tid >> 6] = ssa;
    __syncthreads();
    const float anorm = fmaxf(sqrtf(tmp[0] + tmp[1] + tmp[2] + tmp[3]), 1e-12f);
    const float inv_a = 1.f / anorm;

    if (tid < 128) {
        float g = 0.f;
        for (int t = 0; t < 128; ++t)
            g += partial1[(b * 128 + t) * 132 + tid];
        G[b * 128 + tid] = g * inv_a;
    } else {
        const int c2 = tid - 128;
        float s = 0.f;
        for (int t = 0; t < 128; ++t)
            s += partial2[(b * 128 + t) * 128 + c2];
        kbar[b * 128 + c2] = s * (1.f / 16384.f);
    }
}

// ---------------------------------------------------------------------------
// z kernel. grid 2048, block 256.
// ---------------------------------------------------------------------------
__global__ __launch_bounds__(256) void z_kernel(
    const unsigned short* __restrict__ q, const float* __restrict__ kbar,
    float* __restrict__ z)
{
    const int bid = blockIdx.x;
    const int b   = bid >> 8;
    const int tg  = bid & 255;
    const int tid = threadIdx.x;
    const int t   = tid >> 2;
    const int qt  = tid & 3;
    const int tok = tg * 64 + t;

    const unsigned short* qp = q + ((size_t)b * NN + tok) * 128 + qt * 32;
    const float* kb = kbar + b * 128 + qt * 32;

    float dot0 = 0.f, dot1 = 0.f;
#pragma unroll
    for (int c = 0; c < 4; ++c) {
        const short4v q4a = *(const short4v*)(qp + c * 8);
        const short4v q4b = *(const short4v*)(qp + c * 8 + 4);
        const float4 k4a = *(const float4*)(kb + c * 8);
        const float4 k4b = *(const float4*)(kb + c * 8 + 4);
        float d = bf2f((unsigned short)q4a[0]) * k4a.x + bf2f((unsigned short)q4a[1]) * k4a.y +
                  bf2f((unsigned short)q4a[2]) * k4a.z + bf2f((unsigned short)q4a[3]) * k4a.w +
                  bf2f((unsigned short)q4b[0]) * k4b.x + bf2f((unsigned short)q4b[1]) * k4b.y +
                  bf2f((unsigned short)q4b[2]) * k4b.z + bf2f((unsigned short)q4b[3]) * k4b.w;
        if (c < 2) dot0 += d; else dot1 += d;
    }
    z[((size_t)b * 8 + qt * 2) * NN + tok]     = 1.f / (dot0 + 1e-6f);
    z[((size_t)b * 8 + qt * 2 + 1) * NN + tok] = 1.f / (dot1 + 1e-6f);
}

// ---------------------------------------------------------------------------
// scp (R16, unchanged): channel-major conv + u-part inline + proj MFMA.
// grid 1024, block 256.
// ---------------------------------------------------------------------------
__global__ __launch_bounds__(256, 2) void scp_kernel(
    float* __restrict__ out, const unsigned short* __restrict__ kt,
    const float* __restrict__ z, const float* __restrict__ G,
    const unsigned short* __restrict__ whi, const unsigned short* __restrict__ wlo,
    const float* __restrict__ bp, const float* __restrict__ dwc_w,
    const float* __restrict__ dwc_b)
{
    __shared__ __align__(16) char smem[32768];
    __shared__ float wct[25][16];
    __shared__ float bi[16];
    __shared__ float Gs;

    const int tid  = threadIdx.x;
    const int bid0 = blockIdx.x;
    const int bid  = (bid0 & 7) * 128 + (bid0 >> 3);
    const int cc   = bid & 127;
    const int b    = bid >> 7;
    const int n0   = bid * 128;

    for (int i = tid; i < 400; i += 256)
        wct[i >> 4][i & 15] = dwc_w[(i & 15) * 25 + (i >> 4)];
    if (tid < 16) bi[tid] = dwc_b[tid];
    if (tid == 0) Gs = G[b * 128 + cc];
    __syncthreads();

    const int ch4 = tid >> 3;
    const int xg  = tid & 7;

    float acc[4][16];
#pragma unroll
    for (int c = 0; c < 4; ++c)
#pragma unroll
        for (int i = 0; i < 16; ++i) acc[c][i] = 0.f;

#pragma unroll
    for (int dy = 0; dy < 5; ++dy) {
        const int yy = cc + dy - 2;
        if (yy < 0 || yy > 127) continue;
#pragma unroll
        for (int c = 0; c < 4; ++c) {
            const int ch = ch4 * 4 + c;
            const unsigned short* rowp = kt + ((size_t)b * 128 + ch) * NN
                                            + yy * 128 + xg * 16 - 8;
            float wf[32];
#pragma unroll
            for (int q4 = 0; q4 < 4; ++q4) {
                const bf16x8 v = *(const bf16x8*)(rowp + q4 * 8);
#pragma unroll
                for (int e = 0; e < 8; ++e)
                    wf[q4 * 8 + e] = bf2f((unsigned short)v[e]);
            }
            if (xg == 0) {
#pragma unroll
                for (int e = 0; e < 8; ++e) wf[e] = 0.f;
            }
            if (xg == 7) {
#pragma unroll
                for (int e = 24; e < 32; ++e) wf[e] = 0.f;
            }
            const int d = ch & 15;
#pragma unroll
            for (int dx = 0; dx < 5; ++dx) {
                const float wv = wct[dy * 5 + dx][d];
#pragma unroll
                for (int i = 0; i < 16; ++i)
                    acc[c][i] += wv * wf[i + dx + 6];
            }
        }
    }

    const float Gcc = Gs;
    const unsigned short* kub = kt + ((size_t)b * 128 + cc) * NN;
    const float* zr = z + ((size_t)b * 8 + (cc >> 4)) * NN;
    const int dbase = (ch4 & 3) * 4;
    const float4 b4 = *(const float4*)(&bi[dbase]);
    const float bv[4] = {b4.x, b4.y, b4.z, b4.w};
#pragma unroll
    for (int i = 0; i < 16; ++i) {
        const int r = xg * 16 + i;
        const int toks = r * 128 + ch4 * 4;
        const short4v ku4 = *(const short4v*)(kub + toks);
        const float4 z4 = *(const float4*)(zr + toks);
        const float zz[4] = {z4.x, z4.y, z4.z, z4.w};
        short4v hv;
#pragma unroll
        for (int c = 0; c < 4; ++c) {
            const float f = Gcc * bf2f((unsigned short)ku4[c]) * zz[c] + acc[c][i] + bv[c];
            hv[c] = (short)f2bf(f);
        }
        const int ad = r * 256 + (((ch4 >> 1) * 16) ^ ((r & 7) << 4)) + (ch4 & 1) * 8;
        *(short4v*)(smem + ad) = hv;
    }
    __syncthreads();

    const int w  = tid >> 6;
    const int ll = tid & 63;
    bf16x8 xh[2][4];
    {
        const int lg16 = (ll >> 4) * 16;
#pragma unroll
        for (int n = 0; n < 2; ++n) {
            const int r = w * 32 + n * 16 + (ll & 15);
            const int rb = r * 256;
            const int sw = (r & 7) << 4;
#pragma unroll
            for (int kt2 = 0; kt2 < 4; ++kt2)
                xh[n][kt2] = *(bf16x8*)(smem + rb + ((kt2 * 64 + lg16) ^ sw));
        }
    }
    const int crow = (ll >> 4) * 4;
    f32x4 pacc[8][2];
#pragma unroll
    for (int m = 0; m < 8; ++m)
#pragma unroll
        for (int n = 0; n < 2; ++n) pacc[m][n] = (f32x4)0.f;

#pragma unroll
    for (int m = 0; m < 8; ++m) {
        const int c = m * 16 + (ll & 15);
        bf16x8 ah[4], al[4];
#pragma unroll
        for (int kt2 = 0; kt2 < 4; ++kt2) {
            const int off = 32768 + c * 128 + kt2 * 32 + (ll >> 4) * 8;
            ah[kt2] = *(const bf16x8*)(whi + off);
            al[kt2] = *(const bf16x8*)(wlo + off);
        }
#pragma unroll
        for (int n = 0; n < 2; ++n)
#pragma unroll
            for (int kt2 = 0; kt2 < 4; ++kt2) {
                pacc[m][n] = __builtin_amdgcn_mfma_f32_16x16x32_bf16(ah[kt2], xh[n][kt2], pacc[m][n], 0, 0, 0);
                pacc[m][n] = __builtin_amdgcn_mfma_f32_16x16x32_bf16(al[kt2], xh[n][kt2], pacc[m][n], 0, 0, 0);
            }
    }

#pragma unroll
    for (int m = 0; m < 8; ++m) {
        const float4 bq = *(const float4*)(bp + m * 16 + crow);
        const float bb[4] = {bq.x, bq.y, bq.z, bq.w};
#pragma unroll
        for (int n = 0; n < 2; ++n)
#pragma unroll
            for (int j = 0; j < 4; ++j) pacc[m][n][j] += bb[j];
    }
    __syncthreads();
#pragma unroll
    for (int n = 0; n < 2; ++n) {
        const int t = ll & 15;
        const int rb = w * 8192 + t * 512;
#pragma unroll
        for (int m = 0; m < 8; ++m) {
            const int ad = rb + (((m * 16 + crow) * 4) ^ ((t & 7) << 4));
            *(f32x4*)(smem + ad) = pacc[m][n];
        }
        asm volatile("s_waitcnt lgkmcnt(0)" ::: "memory");
#pragma unroll
        for (int j = 0; j < 8; ++j) {
            const int fid = j * 64 + ll;
            const int row = fid >> 5;
            const int c4  = fid & 31;
            const int rb3 = w * 8192 + row * 512;
            const f32x4 v = *(f32x4*)(smem + rb3 + ((c4 * 16) ^ ((row & 7) << 4)));
            *(f32x4*)(out + (n0 + w * 32 + n * 16 + row) * 128 + c4 * 4) = v;
        }
    }
}

// ---------------------------------------------------------------------------
extern "C" void kernel_launch(void* const* d_in, const int* in_sizes, int n_in,
                              void* d_out, int out_size, void* d_ws, size_t ws_size,
                              hipStream_t stream)
{
    const float* x       = (const float*)d_in[0];
    const float* Wq      = (const float*)d_in[1];
    const float* Wkv     = (const float*)d_in[2];
    const float* Wproj   = (const float*)d_in[3];
    const float* bproj   = (const float*)d_in[4];
    const float* w_g     = (const float*)d_in[5];
    const float* scale   = (const float*)d_in[6];
    const float* pos_enc = (const float*)d_in[7];
    const float* dwc_w   = (const float*)d_in[8];
    const float* dwc_b   = (const float*)d_in[9];
    float* out = (float*)d_out;

    char* ws = (char*)d_ws;
    unsigned short* qbuf = (unsigned short*)(ws);             // 33554432 B
    unsigned short* ktbuf= (unsigned short*)(ws + 33554432);  // 33554432 B
    float* partial1 = (float*)(ws + 67108864);                // 1024*132*4 = 540672 B
    float* partial2 = (float*)(ws + 67649536);                // 1024*128*4 = 524288 B
    float* G        = (float*)(ws + 68173824);                // 4096 B
    float* kbar     = (float*)(ws + 68177920);                // 4096 B
    unsigned short* whi = (unsigned short*)(ws + 68182016);   // 98304 B
    unsigned short* wlo = (unsigned short*)(ws + 68280320);   // 98304 B
    float* sps      = (float*)(ws + 68378624);                // 512 B
    float* zbuf     = (float*)(ws + 68379136);                // 4194304 B

    wprep_kernel<<<dim3(49), dim3(256), 0, stream>>>(
        Wq, Wkv, Wproj, scale, whi, wlo, sps);
    qproj_kernel<<<dim3(1024), dim3(256), 0, stream>>>(
        x, whi, wlo, w_g, sps, qbuf, partial1);
    kproj_kernel<<<dim3(1024), dim3(256), 0, stream>>>(
        x, whi, wlo, sps, pos_enc, ktbuf, partial2);
    reduce_kernel<<<dim3(8), dim3(256), 0, stream>>>(
        partial1, partial2, G, kbar);
    z_kernel<<<dim3(2048), dim3(256), 0, stream>>>(qbuf, kbar, zbuf);
    scp_kernel<<<dim3(1024), dim3(256), 0, stream>>>(
        out, ktbuf, zbuf, G, whi, wlo, bproj, dwc_w, dwc_b);
}